// Round 3
// baseline (2579.785 us; speedup 1.0000x reference)
//
#include <hip/hip_runtime.h>
#include <math.h>

// Problem constants (B=16, T=2048, DIM=512, N_EMBED=4096)
#define N_TOK   32768
#define N_CODE  4096
#define DIM     512

// Coarse GEMM tiling
#define TM 64     // tokens per block
#define TN 256    // codes per tile iteration
#define KC 32     // K chunk

// ---------------------------------------------------------------------------
// numpy pairwise f32 sum over 512 contiguous elements, replicated bit-exactly:
//   pw(512) = (pw128(0)+pw128(1)) + (pw128(2)+pw128(3))
//   pw128(b): r[j] = a[128b+j]; 15x r[j] += a[128b+8i+j]; ((r0+r1)+(r2+r3))+((r4+r5)+(r6+r7))
// Lanes 0..31 each own chain (b = lane>>3, j = lane&7); combine tree done
// redundantly by all lanes from the 32 partials.
__device__ __forceinline__ float pairwise_tree(const float* p) {
    float P[4];
#pragma unroll
    for (int b = 0; b < 4; ++b) {
        float t01 = __fadd_rn(p[b * 8 + 0], p[b * 8 + 1]);
        float t23 = __fadd_rn(p[b * 8 + 2], p[b * 8 + 3]);
        float t45 = __fadd_rn(p[b * 8 + 4], p[b * 8 + 5]);
        float t67 = __fadd_rn(p[b * 8 + 6], p[b * 8 + 7]);
        P[b] = __fadd_rn(__fadd_rn(t01, t23), __fadd_rn(t45, t67));
    }
    return __fadd_rn(__fadd_rn(P[0], P[1]), __fadd_rn(P[2], P[3]));
}

// ---------------------------------------------------------------------------
// K1: per-code f32-replicated norm + t3 (= sum of normalized squares),
//     plus invn for coarse ranking. grid = N_CODE x 64.
__global__ void norms_kernel(const float* __restrict__ embed,
                             float* __restrict__ n_f,
                             float* __restrict__ t3_f,
                             float* __restrict__ invn_f,
                             double* __restrict__ diffsum) {
    __shared__ float part[32];
    int j = blockIdx.x;
    int lane = threadIdx.x;  // 0..63
    const float* e = embed + (size_t)j * DIM;

    if (lane < 32) {
        int base = (lane >> 3) * 128 + (lane & 7);
        float v = e[base];
        float r = __fmul_rn(v, v);
#pragma unroll
        for (int i = 1; i < 16; ++i) {
            float u = e[base + 8 * i];
            r = __fadd_rn(r, __fmul_rn(u, u));
        }
        part[lane] = r;
    }
    __syncthreads();
    float S = pairwise_tree(part);
    float n = __fsqrt_rn(S);
    __syncthreads();   // all lanes done reading part before phase 2 writes

    if (lane < 32) {
        int base = (lane >> 3) * 128 + (lane & 7);
        float w0 = __fdiv_rn(e[base], n);
        float r = __fmul_rn(w0, w0);
#pragma unroll
        for (int i = 1; i < 16; ++i) {
            float w = __fdiv_rn(e[base + 8 * i], n);
            r = __fadd_rn(r, __fmul_rn(w, w));
        }
        part[lane] = r;
    }
    __syncthreads();
    if (lane == 0) {
        float t3 = pairwise_tree(part);
        n_f[j]   = n;
        t3_f[j]  = t3;
        invn_f[j] = 1.0f / n;
        if (j == 0) *diffsum = 0.0;
    }
}

// ---------------------------------------------------------------------------
// K2: fp32 coarse scoring. Each block: 64 tokens vs all 4096 codes.
// score(n,j) = dot(x_n, e_j) * invn_f[j]; keep per-token top-4 candidates.
__global__ __launch_bounds__(256) void coarse_kernel(
        const float* __restrict__ x, const float* __restrict__ embed,
        const float* __restrict__ invn_f, int4* __restrict__ cand) {
    __shared__ __attribute__((aligned(16))) float fT[KC][TM + 4];   // [k][m]
    __shared__ __attribute__((aligned(16))) float eT[KC][TN + 4];   // [k][n]
    __shared__ float mvals[TM][64];
    __shared__ int   midx [TM][64];

    const int tid = threadIdx.x;
    const int tr = tid >> 5;    // 0..7  (token-row group, 8 tokens each)
    const int tc = tid & 31;    // 0..31 (code-col group, 8 codes each)
    const int m0 = blockIdx.x * TM;

    float v1[8], v2[8];
    int   i1[8], i2[8];
#pragma unroll
    for (int i = 0; i < 8; ++i) { v1[i] = -1e30f; v2[i] = -1e30f; i1[i] = 0; i2[i] = 0; }

    for (int nt = 0; nt < N_CODE / TN; ++nt) {
        float acc[8][8];
#pragma unroll
        for (int i = 0; i < 8; ++i)
#pragma unroll
            for (int j = 0; j < 8; ++j) acc[i][j] = 0.0f;

        for (int kc = 0; kc < DIM / KC; ++kc) {
#pragma unroll
            for (int p = 0; p < 2; ++p) {
                int q = tid + p * 256;
                int row = q >> 3;
                int c4  = q & 7;
                float4 v = *(const float4*)&x[(size_t)(m0 + row) * DIM + kc * KC + c4 * 4];
                fT[c4 * 4 + 0][row] = v.x;
                fT[c4 * 4 + 1][row] = v.y;
                fT[c4 * 4 + 2][row] = v.z;
                fT[c4 * 4 + 3][row] = v.w;
            }
#pragma unroll
            for (int p = 0; p < 8; ++p) {
                int q = tid + p * 256;
                int row = q >> 3;
                int c4  = q & 7;
                float4 v = *(const float4*)&embed[(size_t)(nt * TN + row) * DIM + kc * KC + c4 * 4];
                eT[c4 * 4 + 0][row] = v.x;
                eT[c4 * 4 + 1][row] = v.y;
                eT[c4 * 4 + 2][row] = v.z;
                eT[c4 * 4 + 3][row] = v.w;
            }
            __syncthreads();
#pragma unroll 8
            for (int kk = 0; kk < KC; ++kk) {
                float4 a0 = *(const float4*)&fT[kk][tr * 8];
                float4 a1 = *(const float4*)&fT[kk][tr * 8 + 4];
                float4 b0 = *(const float4*)&eT[kk][tc * 8];
                float4 b1 = *(const float4*)&eT[kk][tc * 8 + 4];
                float a[8] = {a0.x, a0.y, a0.z, a0.w, a1.x, a1.y, a1.z, a1.w};
                float b[8] = {b0.x, b0.y, b0.z, b0.w, b1.x, b1.y, b1.z, b1.w};
#pragma unroll
                for (int i = 0; i < 8; ++i)
#pragma unroll
                    for (int j = 0; j < 8; ++j)
                        acc[i][j] = fmaf(a[i], b[j], acc[i][j]);
            }
            __syncthreads();
        }

        const int jbase = nt * TN + tc * 8;
        float inv[8];
#pragma unroll
        for (int j = 0; j < 8; ++j) inv[j] = invn_f[jbase + j];
#pragma unroll
        for (int i = 0; i < 8; ++i) {
#pragma unroll
            for (int j = 0; j < 8; ++j) {
                float s = acc[i][j] * inv[j];
                int idx = jbase + j;
                if (s > v2[i]) {
                    if (s > v1[i]) { v2[i] = v1[i]; i2[i] = i1[i]; v1[i] = s; i1[i] = idx; }
                    else           { v2[i] = s;     i2[i] = idx; }
                }
            }
        }
    }

#pragma unroll
    for (int i = 0; i < 8; ++i) {
        int L = tr * 8 + i;
        mvals[L][tc * 2 + 0] = v1[i];  midx[L][tc * 2 + 0] = i1[i];
        mvals[L][tc * 2 + 1] = v2[i];  midx[L][tc * 2 + 1] = i2[i];
    }
    __syncthreads();
    if (tid < TM) {
        float bv[4] = {-1e30f, -1e30f, -1e30f, -1e30f};
        int   bi[4] = {0x7fffffff, 0x7fffffff, 0x7fffffff, 0x7fffffff};
        for (int t = 0; t < 64; ++t) {
            float v = mvals[tid][t];
            int   id = midx[tid][t];
            int pos = 4;
            while (pos > 0 && (v > bv[pos - 1] ||
                               (v == bv[pos - 1] && id < bi[pos - 1]))) --pos;
            if (pos < 4) {
                for (int sft = 3; sft > pos; --sft) { bv[sft] = bv[sft - 1]; bi[sft] = bi[sft - 1]; }
                bv[pos] = v; bi[pos] = id;
            }
        }
        cand[m0 + tid] = make_int4(bi[0], bi[1], bi[2], bi[3]);
    }
}

// ---------------------------------------------------------------------------
// K3: f32-replicated dist over the 4 candidates:
//   dist = fl32( fl32(t1 - 2*mm) + t3 ),  mm = fl32(exact f64 dot(f, w_hat))
// argmin with lower-index tie-break; gather + MSE.
// one wave per token; grid = N_TOK/4 blocks x 256 threads
__global__ void refine_kernel(const float* __restrict__ x,
                              const float* __restrict__ embed,
                              const float* __restrict__ n_f,
                              const float* __restrict__ t3_f,
                              const int4* __restrict__ cand,
                              float* __restrict__ out,
                              double* __restrict__ diffsum) {
    __shared__ float part[4][32];
    const int wid  = threadIdx.x >> 6;       // 0..3 (wave in block)
    const int lane = threadIdx.x & 63;
    const int tok  = blockIdx.x * 4 + wid;
    const float* f = x + (size_t)tok * DIM;

    // t1 = numpy pairwise f32 sum of f^2
    if (lane < 32) {
        int base = (lane >> 3) * 128 + (lane & 7);
        float v = f[base];
        float r = __fmul_rn(v, v);
#pragma unroll
        for (int i = 1; i < 16; ++i) {
            float u = f[base + 8 * i];
            r = __fadd_rn(r, __fmul_rn(u, u));
        }
        part[wid][lane] = r;
    }
    __syncthreads();
    float t1 = pairwise_tree(part[wid]);

    int4 c4v = cand[tok];
    int cc[4] = {c4v.x, c4v.y, c4v.z, c4v.w};
    float dist[4];
#pragma unroll
    for (int k = 0; k < 4; ++k) {
        const float* e = embed + (size_t)cc[k] * DIM;
        float n = n_f[cc[k]];
        double s = 0.0;
#pragma unroll
        for (int r = 0; r < 8; ++r) {
            int d = lane * 8 + r;
            float wh = __fdiv_rn(e[d], n);       // replicate f32 element of w_hat
            s += (double)f[d] * (double)wh;
        }
#pragma unroll
        for (int off = 32; off > 0; off >>= 1) s += __shfl_xor(s, off);
        float mm = (float)s;                     // round-to-nearest f32
        dist[k] = __fadd_rn(__fsub_rn(t1, __fmul_rn(2.0f, mm)), t3_f[cc[k]]);
    }

    // argmin with lower-index tie-break (np.argmax(-dist) semantics)
    float bd = dist[0]; int bc = cc[0];
#pragma unroll
    for (int k = 1; k < 4; ++k) {
        if (dist[k] < bd || (dist[k] == bd && cc[k] < bc)) { bd = dist[k]; bc = cc[k]; }
    }

    const float* eb = embed + (size_t)bc * DIM;
    double dsum = 0.0;
#pragma unroll
    for (int r = 0; r < DIM / 64; ++r) {
        int d = lane + 64 * r;
        float q = eb[d];
        out[(size_t)tok * DIM + d] = q;   // (quantize + quantize_1)*0.5 == quantize
        double dd = (double)q - (double)f[d];
        dsum += dd * dd;
    }
#pragma unroll
    for (int off = 32; off > 0; off >>= 1) dsum += __shfl_xor(dsum, off);
    if (lane == 0) atomicAdd(diffsum, dsum);
}

// ---------------------------------------------------------------------------
__global__ void finalize_kernel(const double* __restrict__ diffsum,
                                float* __restrict__ out) {
    out[(size_t)N_TOK * DIM] = (float)(*diffsum * (1.0 / ((double)N_TOK * DIM)));
}

// ---------------------------------------------------------------------------
extern "C" void kernel_launch(void* const* d_in, const int* in_sizes, int n_in,
                              void* d_out, int out_size, void* d_ws, size_t ws_size,
                              hipStream_t stream) {
    const float* x     = (const float*)d_in[0];   // [32768, 512]
    const float* embed = (const float*)d_in[1];   // [4096, 512]
    float* out = (float*)d_out;                   // 16777216 + 1 floats

    char* w = (char*)d_ws;
    double* diffsum = (double*)w;                              // 16 B slot
    float*  n_f    = (float*)(w + 16);                         // 4096 * 4
    float*  t3_f   = (float*)(w + 16 + N_CODE * 4);            // 4096 * 4
    float*  invn_f = (float*)(w + 16 + N_CODE * 8);            // 4096 * 4
    int4*   cand   = (int4*) (w + 16 + N_CODE * 12);           // 32768 * 16

    norms_kernel  <<<N_CODE, 64, 0, stream>>>(embed, n_f, t3_f, invn_f, diffsum);
    coarse_kernel <<<N_TOK / TM, 256, 0, stream>>>(x, embed, invn_f, cand);
    refine_kernel <<<N_TOK / 4, 256, 0, stream>>>(x, embed, n_f, t3_f, cand, out, diffsum);
    finalize_kernel<<<1, 1, 0, stream>>>(diffsum, out);
}

// Round 4
// 936.479 us; speedup vs baseline: 2.7548x; 2.7548x over previous
//
#include <hip/hip_runtime.h>
#include <math.h>

// Problem constants (B=16, T=2048, DIM=512, N_EMBED=4096)
#define N_TOK   32768
#define N_CODE  4096
#define DIM     512

// Coarse MFMA tiling
#define CBM 64      // tokens per block
#define CBN 256     // codes per N-tile
#define CBK 64      // K chunk per staging round

typedef __bf16 bf16x8 __attribute__((ext_vector_type(8)));
typedef float  f32x4  __attribute__((ext_vector_type(4)));

__device__ __forceinline__ unsigned short f32_to_bf16_rn(float f) {
    union { float f; unsigned int u; } c; c.f = f;
    unsigned int u = c.u;
    return (unsigned short)((u + 0x7FFFu + ((u >> 16) & 1u)) >> 16);
}

// ---------------------------------------------------------------------------
// numpy pairwise f32 sum over 512 contiguous elements (bit-exact), see R3.
__device__ __forceinline__ float pairwise_tree(const float* p) {
    float P[4];
#pragma unroll
    for (int b = 0; b < 4; ++b) {
        float t01 = __fadd_rn(p[b * 8 + 0], p[b * 8 + 1]);
        float t23 = __fadd_rn(p[b * 8 + 2], p[b * 8 + 3]);
        float t45 = __fadd_rn(p[b * 8 + 4], p[b * 8 + 5]);
        float t67 = __fadd_rn(p[b * 8 + 6], p[b * 8 + 7]);
        P[b] = __fadd_rn(__fadd_rn(t01, t23), __fadd_rn(t45, t67));
    }
    return __fadd_rn(__fadd_rn(P[0], P[1]), __fadd_rn(P[2], P[3]));
}

// ---------------------------------------------------------------------------
// K1: per-code f32-replicated norm + t3; zero diff accumulator.
__global__ void norms_kernel(const float* __restrict__ embed,
                             float* __restrict__ n_f,
                             float* __restrict__ t3_f,
                             double* __restrict__ diffsum) {
    __shared__ float part[32];
    int j = blockIdx.x;
    int lane = threadIdx.x;
    const float* e = embed + (size_t)j * DIM;

    if (lane < 32) {
        int base = (lane >> 3) * 128 + (lane & 7);
        float v = e[base];
        float r = __fmul_rn(v, v);
#pragma unroll
        for (int i = 1; i < 16; ++i) {
            float u = e[base + 8 * i];
            r = __fadd_rn(r, __fmul_rn(u, u));
        }
        part[lane] = r;
    }
    __syncthreads();
    float S = pairwise_tree(part);
    float n = __fsqrt_rn(S);
    __syncthreads();

    if (lane < 32) {
        int base = (lane >> 3) * 128 + (lane & 7);
        float w0 = __fdiv_rn(e[base], n);
        float r = __fmul_rn(w0, w0);
#pragma unroll
        for (int i = 1; i < 16; ++i) {
            float w = __fdiv_rn(e[base + 8 * i], n);
            r = __fadd_rn(r, __fmul_rn(w, w));
        }
        part[lane] = r;
    }
    __syncthreads();
    if (lane == 0) {
        n_f[j]  = n;
        t3_f[j] = pairwise_tree(part);
        if (j == 0) *diffsum = 0.0;
    }
}

// ---------------------------------------------------------------------------
// K2a: x -> bf16 (RN)
__global__ void xcvt_kernel(const float* __restrict__ x, unsigned short* __restrict__ xb) {
    int gid = blockIdx.x * 256 + threadIdx.x;
    float4 v = ((const float4*)x)[gid];
    ushort4 o;
    o.x = f32_to_bf16_rn(v.x); o.y = f32_to_bf16_rn(v.y);
    o.z = f32_to_bf16_rn(v.z); o.w = f32_to_bf16_rn(v.w);
    ((ushort4*)xb)[gid] = o;
}

// K2b: w_hat = e/n (f32, np-exact) -> store f32 (refine) + bf16 (coarse)
__global__ void wcvt_kernel(const float* __restrict__ embed, const float* __restrict__ n_f,
                            float* __restrict__ whf, unsigned short* __restrict__ wb) {
    int gid = blockIdx.x * 256 + threadIdx.x;   // float4 index
    int row = gid >> 7;                         // 128 float4 per row
    float n = n_f[row];
    float4 e = ((const float4*)embed)[gid];
    float4 w;
    w.x = __fdiv_rn(e.x, n); w.y = __fdiv_rn(e.y, n);
    w.z = __fdiv_rn(e.z, n); w.w = __fdiv_rn(e.w, n);
    ((float4*)whf)[gid] = w;
    ushort4 o;
    o.x = f32_to_bf16_rn(w.x); o.y = f32_to_bf16_rn(w.y);
    o.z = f32_to_bf16_rn(w.z); o.w = f32_to_bf16_rn(w.w);
    ((ushort4*)wb)[gid] = o;
}

// ---------------------------------------------------------------------------
__device__ __forceinline__ void top8_insert(float s, int idx, float (&bv)[8], int (&bi)[8]) {
    if (s > bv[7]) {
#pragma unroll
        for (int k = 7; k > 0; --k) {
            bool up = s > bv[k - 1];
            float nv = (s > bv[k]) ? s : bv[k];
            int   ni = (s > bv[k]) ? idx : bi[k];
            bv[k] = up ? bv[k - 1] : nv;
            bi[k] = up ? bi[k - 1] : ni;
        }
        bool up0 = s > bv[0];
        bi[0] = up0 ? idx : bi[0];
        bv[0] = up0 ? s : bv[0];
    }
}

// ---------------------------------------------------------------------------
// K3: bf16 MFMA coarse scoring + fused per-token top-8.
// Block: 64 tokens x all 4096 codes (16 N-tiles of 256). 2 waves, each 64x128.
__global__ __launch_bounds__(128, 2) void coarse_kernel(
        const unsigned short* __restrict__ xb,
        const unsigned short* __restrict__ wb,
        int* __restrict__ cand) {
    __shared__ __attribute__((aligned(16))) char smem[40960];
    unsigned short* sA = (unsigned short*)smem;            // [64][64] bf16, chunk-swizzled
    unsigned short* sB = (unsigned short*)(smem + 8192);   // [256][64] bf16, chunk-swizzled
    float* sS = (float*)smem;                              // scores [64][130] (union)

    const int tid = threadIdx.x;
    const int w   = tid >> 6;          // wave id 0/1
    const int l   = tid & 63;
    const int m0  = blockIdx.x * CBM;

    const int srow   = l >> 3;               // row within an 8-row staging group
    const int schunk = (l & 7) ^ srow;       // XOR-swizzled source 16B-chunk

    float bv[8]; int bi[8];
#pragma unroll
    for (int k = 0; k < 8; ++k) { bv[k] = -1e30f; bi[k] = k; }

    for (int nt = 0; nt < N_CODE / CBN; ++nt) {
        f32x4 acc[4][8];
#pragma unroll
        for (int i = 0; i < 4; ++i)
#pragma unroll
            for (int j = 0; j < 8; ++j) acc[i][j] = {0.0f, 0.0f, 0.0f, 0.0f};

        for (int kc = 0; kc < DIM / CBK; ++kc) {
            __syncthreads();   // protect LDS from prior readers
            // stage A: 64 rows x 128B; wave w stages rows [w*32, w*32+32)
#pragma unroll
            for (int c = 0; c < 4; ++c) {
                int r0 = w * 32 + c * 8;
                const unsigned short* gp =
                    xb + (size_t)(m0 + r0 + srow) * DIM + kc * CBK + schunk * 8;
                __builtin_amdgcn_global_load_lds(
                    (const __attribute__((address_space(1))) void*)gp,
                    (__attribute__((address_space(3))) void*)(sA + r0 * 64), 16, 0, 0);
            }
            // stage B: 256 rows x 128B; wave w stages rows [w*128, w*128+128)
#pragma unroll
            for (int c = 0; c < 16; ++c) {
                int r0 = w * 128 + c * 8;
                const unsigned short* gp =
                    wb + (size_t)(nt * CBN + r0 + srow) * DIM + kc * CBK + schunk * 8;
                __builtin_amdgcn_global_load_lds(
                    (const __attribute__((address_space(1))) void*)gp,
                    (__attribute__((address_space(3))) void*)(sB + r0 * 64), 16, 0, 0);
            }
            __syncthreads();   // staged data visible

#pragma unroll
            for (int ks = 0; ks < 2; ++ks) {
                const int q = ks * 4 + (l >> 4);   // logical 16B k-chunk 0..7
                const int mrow = l & 15;
                bf16x8 af[4], bfr[8];
#pragma unroll
                for (int i = 0; i < 4; ++i) {
                    int m = i * 16 + mrow;
                    af[i] = *(const bf16x8*)(sA + m * 64 + (q ^ (m & 7)) * 8);
                }
#pragma unroll
                for (int j = 0; j < 8; ++j) {
                    int n = w * 128 + j * 16 + mrow;
                    bfr[j] = *(const bf16x8*)(sB + n * 64 + (q ^ (n & 7)) * 8);
                }
#pragma unroll
                for (int i = 0; i < 4; ++i)
#pragma unroll
                    for (int j = 0; j < 8; ++j)
                        acc[i][j] = __builtin_amdgcn_mfma_f32_16x16x32_bf16(
                            af[i], bfr[j], acc[i][j], 0, 0, 0);
            }
        }

        // selection: two rounds, one per wave's 128-col strip
#pragma unroll
        for (int rnd = 0; rnd < 2; ++rnd) {
            __syncthreads();   // staging/frag reads (or prior scan) done
            if (w == rnd) {
                int q = l >> 4, c = l & 15;
#pragma unroll
                for (int i = 0; i < 4; ++i)
#pragma unroll
                    for (int j = 0; j < 8; ++j)
#pragma unroll
                        for (int r = 0; r < 4; ++r)
                            sS[(i * 16 + q * 4 + r) * 130 + j * 16 + c] = acc[i][j][r];
            }
            __syncthreads();
            int tk = tid & 63, hf = tid >> 6;
            const float2* sr = (const float2*)(sS + tk * 130 + hf * 64);
            int ib = nt * CBN + rnd * 128 + hf * 64;
#pragma unroll 8
            for (int c2 = 0; c2 < 32; ++c2) {
                float2 v = sr[c2];
                top8_insert(v.x, ib + 2 * c2 + 0, bv, bi);
                top8_insert(v.y, ib + 2 * c2 + 1, bv, bi);
            }
        }
    }

    // merge the two col-halves per token
    __syncthreads();
    float* mv = sS;                    // 64*8 floats
    int*   mi = (int*)(sS + 512);      // 64*8 ints
    if (tid >= 64) {
#pragma unroll
        for (int k = 0; k < 8; ++k) {
            mv[(tid - 64) * 8 + k] = bv[k];
            mi[(tid - 64) * 8 + k] = bi[k];
        }
    }
    __syncthreads();
    if (tid < 64) {
#pragma unroll
        for (int k = 0; k < 8; ++k) top8_insert(mv[tid * 8 + k], mi[tid * 8 + k], bv, bi);
        int* cp = cand + (size_t)(m0 + tid) * 8;
#pragma unroll
        for (int k = 0; k < 8; ++k) cp[k] = bi[k];
    }
}

// ---------------------------------------------------------------------------
// K4: f32-replicated dist over 8 candidates (np-exact, as R3), gather + MSE.
__global__ void refine_kernel(const float* __restrict__ x,
                              const float* __restrict__ embed,
                              const float* __restrict__ whf,
                              const float* __restrict__ t3_f,
                              const int* __restrict__ cand,
                              float* __restrict__ out,
                              double* __restrict__ diffsum) {
    __shared__ float part[4][32];
    const int wid  = threadIdx.x >> 6;
    const int lane = threadIdx.x & 63;
    const int tok  = blockIdx.x * 4 + wid;
    const float* f = x + (size_t)tok * DIM;

    if (lane < 32) {
        int base = (lane >> 3) * 128 + (lane & 7);
        float v = f[base];
        float r = __fmul_rn(v, v);
#pragma unroll
        for (int i = 1; i < 16; ++i) {
            float u = f[base + 8 * i];
            r = __fadd_rn(r, __fmul_rn(u, u));
        }
        part[wid][lane] = r;
    }
    __syncthreads();
    float t1 = pairwise_tree(part[wid]);

    float4 f0 = *(const float4*)(f + lane * 8);
    float4 f1 = *(const float4*)(f + lane * 8 + 4);

    float bd = 1e30f; int bc = 0x7fffffff;
    const int* cp = cand + (size_t)tok * 8;
#pragma unroll
    for (int k = 0; k < 8; ++k) {
        int c = cp[k];
        const float* wh = whf + (size_t)c * DIM + lane * 8;
        float4 w0 = *(const float4*)wh;
        float4 w1 = *(const float4*)(wh + 4);
        double s = (double)f0.x * w0.x + (double)f0.y * w0.y
                 + (double)f0.z * w0.z + (double)f0.w * w0.w
                 + (double)f1.x * w1.x + (double)f1.y * w1.y
                 + (double)f1.z * w1.z + (double)f1.w * w1.w;
#pragma unroll
        for (int off = 32; off > 0; off >>= 1) s += __shfl_xor(s, off);
        float mm = (float)s;
        float dist = __fadd_rn(__fsub_rn(t1, __fmul_rn(2.0f, mm)), t3_f[c]);
        if (dist < bd || (dist == bd && c < bc)) { bd = dist; bc = c; }
    }

    const float* eb = embed + (size_t)bc * DIM;
    double dsum = 0.0;
#pragma unroll
    for (int r = 0; r < DIM / 64; ++r) {
        int d = lane + 64 * r;
        float q = eb[d];
        out[(size_t)tok * DIM + d] = q;   // (quantize + quantize_1)*0.5 == quantize
        double dd = (double)q - (double)f[d];
        dsum += dd * dd;
    }
#pragma unroll
    for (int off = 32; off > 0; off >>= 1) dsum += __shfl_xor(dsum, off);
    if (lane == 0) atomicAdd(diffsum, dsum);
}

// ---------------------------------------------------------------------------
__global__ void finalize_kernel(const double* __restrict__ diffsum,
                                float* __restrict__ out) {
    out[(size_t)N_TOK * DIM] = (float)(*diffsum * (1.0 / ((double)N_TOK * DIM)));
}

// ---------------------------------------------------------------------------
extern "C" void kernel_launch(void* const* d_in, const int* in_sizes, int n_in,
                              void* d_out, int out_size, void* d_ws, size_t ws_size,
                              hipStream_t stream) {
    const float* x     = (const float*)d_in[0];   // [32768, 512]
    const float* embed = (const float*)d_in[1];   // [4096, 512]
    float* out = (float*)d_out;                   // 16777216 + 1 floats

    char* wsb = (char*)d_ws;
    double* diffsum       = (double*)wsb;                         // 16 B
    float*  n_f           = (float*)(wsb + 16);                   // 16 KB
    float*  t3_f          = (float*)(wsb + 16 + 16384);           // 16 KB
    int*    cand          = (int*)  (wsb + 16 + 32768);           // 1 MB
    unsigned short* xb    = (unsigned short*)(wsb + 16 + 32768 + 1048576);           // 32 MB
    unsigned short* wb    = (unsigned short*)(wsb + 16 + 32768 + 1048576 + 33554432);// 4 MB
    float*  whf           = (float*)(wsb + 16 + 32768 + 1048576 + 33554432 + 4194304); // 8 MB

    xcvt_kernel    <<<16384, 256, 0, stream>>>(x, xb);
    norms_kernel   <<<N_CODE, 64, 0, stream>>>(embed, n_f, t3_f, diffsum);
    wcvt_kernel    <<<2048, 256, 0, stream>>>(embed, n_f, whf, wb);
    coarse_kernel  <<<N_TOK / CBM, 128, 0, stream>>>(xb, wb, cand);
    refine_kernel  <<<N_TOK / 4, 256, 0, stream>>>(x, embed, whf, t3_f, cand, out, diffsum);
    finalize_kernel<<<1, 1, 0, stream>>>(diffsum, out);
}

// Round 5
// 591.680 us; speedup vs baseline: 4.3601x; 1.5827x over previous
//
#include <hip/hip_runtime.h>
#include <math.h>

// Problem constants (B=16, T=2048, DIM=512, N_EMBED=4096)
#define N_TOK   32768
#define N_CODE  4096
#define DIM     512

// Coarse MFMA tiling
#define CBM 64      // tokens per block
#define CBN 512     // codes per N-tile (4 wave-strips of 128)
#define CBK 64      // K chunk per staging round
#define NT_STEPS (N_CODE / CBN)   // 8
#define KC_STEPS (DIM / CBK)      // 8

typedef __bf16 bf16x8 __attribute__((ext_vector_type(8)));
typedef float  f32x4  __attribute__((ext_vector_type(4)));

__device__ __forceinline__ unsigned short f32_to_bf16_rn(float f) {
    union { float f; unsigned int u; } c; c.f = f;
    unsigned int u = c.u;
    return (unsigned short)((u + 0x7FFFu + ((u >> 16) & 1u)) >> 16);
}

// ---------------------------------------------------------------------------
// numpy pairwise f32 sum over 512 contiguous elements (bit-exact), see R3.
__device__ __forceinline__ float pairwise_tree(const float* p) {
    float P[4];
#pragma unroll
    for (int b = 0; b < 4; ++b) {
        float t01 = __fadd_rn(p[b * 8 + 0], p[b * 8 + 1]);
        float t23 = __fadd_rn(p[b * 8 + 2], p[b * 8 + 3]);
        float t45 = __fadd_rn(p[b * 8 + 4], p[b * 8 + 5]);
        float t67 = __fadd_rn(p[b * 8 + 6], p[b * 8 + 7]);
        P[b] = __fadd_rn(__fadd_rn(t01, t23), __fadd_rn(t45, t67));
    }
    return __fadd_rn(__fadd_rn(P[0], P[1]), __fadd_rn(P[2], P[3]));
}

// ---------------------------------------------------------------------------
// K1: per-code f32-replicated norm + t3.
__global__ void norms_kernel(const float* __restrict__ embed,
                             float* __restrict__ n_f,
                             float* __restrict__ t3_f) {
    __shared__ float part[32];
    int j = blockIdx.x;
    int lane = threadIdx.x;
    const float* e = embed + (size_t)j * DIM;

    if (lane < 32) {
        int base = (lane >> 3) * 128 + (lane & 7);
        float v = e[base];
        float r = __fmul_rn(v, v);
#pragma unroll
        for (int i = 1; i < 16; ++i) {
            float u = e[base + 8 * i];
            r = __fadd_rn(r, __fmul_rn(u, u));
        }
        part[lane] = r;
    }
    __syncthreads();
    float S = pairwise_tree(part);
    float n = __fsqrt_rn(S);
    __syncthreads();

    if (lane < 32) {
        int base = (lane >> 3) * 128 + (lane & 7);
        float w0 = __fdiv_rn(e[base], n);
        float r = __fmul_rn(w0, w0);
#pragma unroll
        for (int i = 1; i < 16; ++i) {
            float w = __fdiv_rn(e[base + 8 * i], n);
            r = __fadd_rn(r, __fmul_rn(w, w));
        }
        part[lane] = r;
    }
    __syncthreads();
    if (lane == 0) {
        n_f[j]  = n;
        t3_f[j] = pairwise_tree(part);
    }
}

// ---------------------------------------------------------------------------
// K2a: x -> bf16 (RN)
__global__ void xcvt_kernel(const float* __restrict__ x, unsigned short* __restrict__ xb) {
    int gid = blockIdx.x * 256 + threadIdx.x;
    float4 v = ((const float4*)x)[gid];
    ushort4 o;
    o.x = f32_to_bf16_rn(v.x); o.y = f32_to_bf16_rn(v.y);
    o.z = f32_to_bf16_rn(v.z); o.w = f32_to_bf16_rn(v.w);
    ((ushort4*)xb)[gid] = o;
}

// K2b: w_hat = e/n (f32, np-exact) -> f32 (refine) + bf16 (coarse)
__global__ void wcvt_kernel(const float* __restrict__ embed, const float* __restrict__ n_f,
                            float* __restrict__ whf, unsigned short* __restrict__ wb) {
    int gid = blockIdx.x * 256 + threadIdx.x;
    int row = gid >> 7;
    float n = n_f[row];
    float4 e = ((const float4*)embed)[gid];
    float4 w;
    w.x = __fdiv_rn(e.x, n); w.y = __fdiv_rn(e.y, n);
    w.z = __fdiv_rn(e.z, n); w.w = __fdiv_rn(e.w, n);
    ((float4*)whf)[gid] = w;
    ushort4 o;
    o.x = f32_to_bf16_rn(w.x); o.y = f32_to_bf16_rn(w.y);
    o.z = f32_to_bf16_rn(w.z); o.w = f32_to_bf16_rn(w.w);
    ((ushort4*)wb)[gid] = o;
}

// ---------------------------------------------------------------------------
__device__ __forceinline__ void top8_insert(float s, int idx, float (&bv)[8], int (&bi)[8]) {
    if (s > bv[7]) {
#pragma unroll
        for (int k = 7; k > 0; --k) {
            bool up = s > bv[k - 1];
            float nv = (s > bv[k]) ? s : bv[k];
            int   ni = (s > bv[k]) ? idx : bi[k];
            bv[k] = up ? bv[k - 1] : nv;
            bi[k] = up ? bi[k - 1] : ni;
        }
        bool up0 = s > bv[0];
        bi[0] = up0 ? idx : bi[0];
        bv[0] = up0 ? s : bv[0];
    }
}

// ---------------------------------------------------------------------------
// K3: bf16 MFMA coarse scoring + fused per-token top-8.
// Block: 256 threads (4 waves), 64 tokens x all 4096 codes (8 N-tiles of 512).
// Wave w computes the 64x128 strip at cols nt*512 + w*128.
__global__ __launch_bounds__(256, 2) void coarse_kernel(
        const unsigned short* __restrict__ xb,
        const unsigned short* __restrict__ wb,
        int* __restrict__ cand) {
    __shared__ __attribute__((aligned(16))) char smem[73728];
    unsigned short* sA = (unsigned short*)smem;            // [64][64] bf16, chunk-swizzled
    unsigned short* sB = (unsigned short*)(smem + 8192);   // [512][64] bf16, chunk-swizzled
    float* sS = (float*)smem;                              // 4 strips x [64][68] f32 (reuse)
    float* mv = (float*)smem;                              // merge vals [64][32] (reuse)
    int*   mi = (int*)(smem + 8192);                       // merge idx  [64][32] (reuse)

    const int tid = threadIdx.x;
    const int w   = tid >> 6;          // wave id 0..3
    const int l   = tid & 63;
    const int m0  = blockIdx.x * CBM;

    const int srow   = l >> 3;               // row within an 8-row staging group
    const int schunk = (l & 7) ^ srow;       // XOR-swizzled source 16B-chunk
    const int mrow   = l & 15;
    const int kq     = l >> 4;               // 0..3

    float bv[8]; int bi[8];
#pragma unroll
    for (int k = 0; k < 8; ++k) { bv[k] = -1e30f; bi[k] = k; }

    for (int nt = 0; nt < NT_STEPS; ++nt) {
        f32x4 acc[4][8];
#pragma unroll
        for (int i = 0; i < 4; ++i)
#pragma unroll
            for (int j = 0; j < 8; ++j) acc[i][j] = {0.0f, 0.0f, 0.0f, 0.0f};

        for (int kc = 0; kc < KC_STEPS; ++kc) {
            __syncthreads();   // prior LDS readers (frags / scan) done
            // stage A: wave w stages rows [w*16, w*16+16)
#pragma unroll
            for (int c = 0; c < 2; ++c) {
                int r0 = w * 16 + c * 8;
                const unsigned short* gp =
                    xb + (size_t)(m0 + r0 + srow) * DIM + kc * CBK + schunk * 8;
                __builtin_amdgcn_global_load_lds(
                    (const __attribute__((address_space(1))) void*)gp,
                    (__attribute__((address_space(3))) void*)(sA + r0 * 64), 16, 0, 0);
            }
            // stage B: wave w stages rows [w*128, w*128+128)
#pragma unroll
            for (int c = 0; c < 16; ++c) {
                int r0 = w * 128 + c * 8;
                const unsigned short* gp =
                    wb + (size_t)(nt * CBN + r0 + srow) * DIM + kc * CBK + schunk * 8;
                __builtin_amdgcn_global_load_lds(
                    (const __attribute__((address_space(1))) void*)gp,
                    (__attribute__((address_space(3))) void*)(sB + r0 * 64), 16, 0, 0);
            }
            __syncthreads();   // staged data visible

#pragma unroll
            for (int ks = 0; ks < 2; ++ks) {
                const int q = ks * 4 + kq;     // logical 16B k-chunk 0..7
                bf16x8 af[4], bfr[8];
#pragma unroll
                for (int i = 0; i < 4; ++i) {
                    int m = i * 16 + mrow;
                    af[i] = *(const bf16x8*)(sA + m * 64 + (q ^ (m & 7)) * 8);
                }
#pragma unroll
                for (int j = 0; j < 8; ++j) {
                    int n = w * 128 + j * 16 + mrow;
                    bfr[j] = *(const bf16x8*)(sB + n * 64 + (q ^ (n & 7)) * 8);
                }
#pragma unroll
                for (int i = 0; i < 4; ++i)
#pragma unroll
                    for (int j = 0; j < 8; ++j)
                        acc[i][j] = __builtin_amdgcn_mfma_f32_16x16x32_bf16(
                            af[i], bfr[j], acc[i][j], 0, 0, 0);
            }
        }

        // selection: 2 half-strip rounds; all 4 waves dump their own region
#pragma unroll
        for (int h = 0; h < 2; ++h) {
            __syncthreads();   // frag reads (h=0) / previous scan (h=1) done
            float* strip = sS + w * (64 * 68);
#pragma unroll
            for (int i = 0; i < 4; ++i)
#pragma unroll
                for (int jj = 0; jj < 4; ++jj) {
                    const int j = h * 4 + jj;
#pragma unroll
                    for (int r = 0; r < 4; ++r)
                        strip[(i * 16 + kq * 4 + r) * 68 + jj * 16 + mrow] = acc[i][j][r];
                }
            __syncthreads();
            // scan: thread (tok = tid&63, qq = tid>>6) scans strip qq's 64 cols
            int tok = tid & 63, qq = tid >> 6;
            const float4* sr = (const float4*)(sS + qq * (64 * 68) + tok * 68);
            int ib = nt * CBN + qq * 128 + h * 64;
#pragma unroll 4
            for (int c4 = 0; c4 < 16; ++c4) {
                float4 v = sr[c4];
                top8_insert(v.x, ib + c4 * 4 + 0, bv, bi);
                top8_insert(v.y, ib + c4 * 4 + 1, bv, bi);
                top8_insert(v.z, ib + c4 * 4 + 2, bv, bi);
                top8_insert(v.w, ib + c4 * 4 + 3, bv, bi);
            }
        }
    }

    // merge the 4 col-quarter top-8 lists per token
    __syncthreads();
    {
        int tok = tid & 63, qq = tid >> 6;
#pragma unroll
        for (int k = 0; k < 8; ++k) {
            mv[tok * 32 + qq * 8 + k] = bv[k];
            mi[tok * 32 + qq * 8 + k] = bi[k];
        }
    }
    __syncthreads();
    if (tid < 64) {
        float fv[8]; int fi[8];
#pragma unroll
        for (int k = 0; k < 8; ++k) { fv[k] = -1e30f; fi[k] = k; }
        for (int t = 0; t < 32; ++t) top8_insert(mv[tid * 32 + t], mi[tid * 32 + t], fv, fi);
        int* cp = cand + (size_t)(m0 + tid) * 8;
#pragma unroll
        for (int k = 0; k < 8; ++k) cp[k] = fi[k];
    }
}

// ---------------------------------------------------------------------------
// K4: f32-replicated dist over 8 candidates (np-exact), gather + MSE partial.
// One wave per token; per-BLOCK partial sum (no global atomics).
__global__ void refine_kernel(const float* __restrict__ x,
                              const float* __restrict__ embed,
                              const float* __restrict__ whf,
                              const float* __restrict__ t3_f,
                              const int* __restrict__ cand,
                              float* __restrict__ out,
                              double* __restrict__ partial) {
    __shared__ float part[4][32];
    __shared__ double wsum[4];
    const int wid  = threadIdx.x >> 6;
    const int lane = threadIdx.x & 63;
    const int tok  = blockIdx.x * 4 + wid;
    const float* f = x + (size_t)tok * DIM;

    if (lane < 32) {
        int base = (lane >> 3) * 128 + (lane & 7);
        float v = f[base];
        float r = __fmul_rn(v, v);
#pragma unroll
        for (int i = 1; i < 16; ++i) {
            float u = f[base + 8 * i];
            r = __fadd_rn(r, __fmul_rn(u, u));
        }
        part[wid][lane] = r;
    }
    __syncthreads();
    float t1 = pairwise_tree(part[wid]);

    float4 f0 = *(const float4*)(f + lane * 8);
    float4 f1 = *(const float4*)(f + lane * 8 + 4);

    float bd = 1e30f; int bc = 0x7fffffff;
    const int* cp = cand + (size_t)tok * 8;
#pragma unroll
    for (int k = 0; k < 8; ++k) {
        int c = cp[k];
        const float* wh = whf + (size_t)c * DIM + lane * 8;
        float4 w0 = *(const float4*)wh;
        float4 w1 = *(const float4*)(wh + 4);
        double s = (double)f0.x * w0.x + (double)f0.y * w0.y
                 + (double)f0.z * w0.z + (double)f0.w * w0.w
                 + (double)f1.x * w1.x + (double)f1.y * w1.y
                 + (double)f1.z * w1.z + (double)f1.w * w1.w;
#pragma unroll
        for (int off = 32; off > 0; off >>= 1) s += __shfl_xor(s, off);
        float mm = (float)s;
        float dist = __fadd_rn(__fsub_rn(t1, __fmul_rn(2.0f, mm)), t3_f[c]);
        if (dist < bd || (dist == bd && c < bc)) { bd = dist; bc = c; }
    }

    const float* eb = embed + (size_t)bc * DIM;
    double dsum = 0.0;
#pragma unroll
    for (int r = 0; r < DIM / 64; ++r) {
        int d = lane + 64 * r;
        float q = eb[d];
        out[(size_t)tok * DIM + d] = q;   // (quantize + quantize_1)*0.5 == quantize
        double dd = (double)q - (double)f[d];
        dsum += dd * dd;
    }
#pragma unroll
    for (int off = 32; off > 0; off >>= 1) dsum += __shfl_xor(dsum, off);
    if (lane == 0) wsum[wid] = dsum;
    __syncthreads();
    if (threadIdx.x == 0)
        partial[blockIdx.x] = wsum[0] + wsum[1] + wsum[2] + wsum[3];
}

// ---------------------------------------------------------------------------
__global__ void finalize_kernel(const double* __restrict__ partial,
                                float* __restrict__ out) {
    __shared__ double acc[4];
    int tid = threadIdx.x;
    double s = 0.0;
    for (int i = tid; i < N_TOK / 4; i += 256) s += partial[i];
#pragma unroll
    for (int off = 32; off > 0; off >>= 1) s += __shfl_xor(s, off);
    if ((tid & 63) == 0) acc[tid >> 6] = s;
    __syncthreads();
    if (tid == 0)
        out[(size_t)N_TOK * DIM] =
            (float)((acc[0] + acc[1] + acc[2] + acc[3]) * (1.0 / ((double)N_TOK * DIM)));
}

// ---------------------------------------------------------------------------
extern "C" void kernel_launch(void* const* d_in, const int* in_sizes, int n_in,
                              void* d_out, int out_size, void* d_ws, size_t ws_size,
                              hipStream_t stream) {
    const float* x     = (const float*)d_in[0];   // [32768, 512]
    const float* embed = (const float*)d_in[1];   // [4096, 512]
    float* out = (float*)d_out;                   // 16777216 + 1 floats

    char* wsb = (char*)d_ws;
    double* partial       = (double*)wsb;                          // 64 KB (8192 f64)
    float*  n_f           = (float*)(wsb + 65536);                 // 16 KB
    float*  t3_f          = (float*)(wsb + 65536 + 16384);         // 16 KB
    int*    cand          = (int*)  (wsb + 65536 + 32768);         // 1 MB
    unsigned short* xb    = (unsigned short*)(wsb + 65536 + 32768 + 1048576);            // 32 MB
    unsigned short* wb    = (unsigned short*)(wsb + 65536 + 32768 + 1048576 + 33554432); // 4 MB
    float*  whf           = (float*)(wsb + 65536 + 32768 + 1048576 + 33554432 + 4194304);// 8 MB

    xcvt_kernel    <<<16384, 256, 0, stream>>>(x, xb);
    norms_kernel   <<<N_CODE, 64, 0, stream>>>(embed, n_f, t3_f);
    wcvt_kernel    <<<2048, 256, 0, stream>>>(embed, n_f, whf, wb);
    coarse_kernel  <<<N_TOK / CBM, 256, 0, stream>>>(xb, wb, cand);
    refine_kernel  <<<N_TOK / 4, 256, 0, stream>>>(x, embed, whf, t3_f, cand, out, partial);
    finalize_kernel<<<1, 256, 0, stream>>>(partial, out);
}

// Round 6
// 591.042 us; speedup vs baseline: 4.3648x; 1.0011x over previous
//
#include <hip/hip_runtime.h>
#include <math.h>

// Problem constants (B=16, T=2048, DIM=512, N_EMBED=4096)
#define N_TOK   32768
#define N_CODE  4096
#define DIM     512

// Coarse MFMA tiling: block = 64 tokens x 2048 codes (one N-half)
#define CBM 64
#define NHALF 2048
#define CBN 256                   // codes per nt step
#define CBK 64                    // K chunk per staging round
#define NT_STEPS (NHALF / CBN)    // 8
#define KC_STEPS (DIM / CBK)      // 8
#define SPITCH 36                 // score strip pitch (floats), 16B aligned

typedef __bf16 bf16x8 __attribute__((ext_vector_type(8)));
typedef float  f32x4  __attribute__((ext_vector_type(4)));

__device__ __forceinline__ unsigned short f32_to_bf16_rn(float f) {
    union { float f; unsigned int u; } c; c.f = f;
    unsigned int u = c.u;
    return (unsigned short)((u + 0x7FFFu + ((u >> 16) & 1u)) >> 16);
}

// ---------------------------------------------------------------------------
// numpy pairwise f32 sum over 512 contiguous elements (bit-exact), see R3.
__device__ __forceinline__ float pairwise_tree(const float* p) {
    float P[4];
#pragma unroll
    for (int b = 0; b < 4; ++b) {
        float t01 = __fadd_rn(p[b * 8 + 0], p[b * 8 + 1]);
        float t23 = __fadd_rn(p[b * 8 + 2], p[b * 8 + 3]);
        float t45 = __fadd_rn(p[b * 8 + 4], p[b * 8 + 5]);
        float t67 = __fadd_rn(p[b * 8 + 6], p[b * 8 + 7]);
        P[b] = __fadd_rn(__fadd_rn(t01, t23), __fadd_rn(t45, t67));
    }
    return __fadd_rn(__fadd_rn(P[0], P[1]), __fadd_rn(P[2], P[3]));
}

// ---------------------------------------------------------------------------
// K1: per-code f32-replicated norm + t3.
__global__ void norms_kernel(const float* __restrict__ embed,
                             float* __restrict__ n_f,
                             float* __restrict__ t3_f) {
    __shared__ float part[32];
    int j = blockIdx.x;
    int lane = threadIdx.x;
    const float* e = embed + (size_t)j * DIM;

    if (lane < 32) {
        int base = (lane >> 3) * 128 + (lane & 7);
        float v = e[base];
        float r = __fmul_rn(v, v);
#pragma unroll
        for (int i = 1; i < 16; ++i) {
            float u = e[base + 8 * i];
            r = __fadd_rn(r, __fmul_rn(u, u));
        }
        part[lane] = r;
    }
    __syncthreads();
    float S = pairwise_tree(part);
    float n = __fsqrt_rn(S);
    __syncthreads();

    if (lane < 32) {
        int base = (lane >> 3) * 128 + (lane & 7);
        float w0 = __fdiv_rn(e[base], n);
        float r = __fmul_rn(w0, w0);
#pragma unroll
        for (int i = 1; i < 16; ++i) {
            float w = __fdiv_rn(e[base + 8 * i], n);
            r = __fadd_rn(r, __fmul_rn(w, w));
        }
        part[lane] = r;
    }
    __syncthreads();
    if (lane == 0) {
        n_f[j]  = n;
        t3_f[j] = pairwise_tree(part);
    }
}

// ---------------------------------------------------------------------------
// K2a: x -> bf16 (RN)
__global__ void xcvt_kernel(const float* __restrict__ x, unsigned short* __restrict__ xb) {
    int gid = blockIdx.x * 256 + threadIdx.x;
    float4 v = ((const float4*)x)[gid];
    ushort4 o;
    o.x = f32_to_bf16_rn(v.x); o.y = f32_to_bf16_rn(v.y);
    o.z = f32_to_bf16_rn(v.z); o.w = f32_to_bf16_rn(v.w);
    ((ushort4*)xb)[gid] = o;
}

// K2b: w_hat = e/n (f32, np-exact) -> f32 (refine) + bf16 (coarse)
__global__ void wcvt_kernel(const float* __restrict__ embed, const float* __restrict__ n_f,
                            float* __restrict__ whf, unsigned short* __restrict__ wb) {
    int gid = blockIdx.x * 256 + threadIdx.x;
    int row = gid >> 7;
    float n = n_f[row];
    float4 e = ((const float4*)embed)[gid];
    float4 w;
    w.x = __fdiv_rn(e.x, n); w.y = __fdiv_rn(e.y, n);
    w.z = __fdiv_rn(e.z, n); w.w = __fdiv_rn(e.w, n);
    ((float4*)whf)[gid] = w;
    ushort4 o;
    o.x = f32_to_bf16_rn(w.x); o.y = f32_to_bf16_rn(w.y);
    o.z = f32_to_bf16_rn(w.z); o.w = f32_to_bf16_rn(w.w);
    ((ushort4*)wb)[gid] = o;
}

// ---------------------------------------------------------------------------
__device__ __forceinline__ void top8_insert(float s, int idx, float (&bv)[8], int (&bi)[8]) {
    if (s > bv[7]) {
#pragma unroll
        for (int k = 7; k > 0; --k) {
            bool up = s > bv[k - 1];
            float nv = (s > bv[k]) ? s : bv[k];
            int   ni = (s > bv[k]) ? idx : bi[k];
            bv[k] = up ? bv[k - 1] : nv;
            bi[k] = up ? bi[k - 1] : ni;
        }
        bool up0 = s > bv[0];
        bi[0] = up0 ? idx : bi[0];
        bv[0] = up0 ? s : bv[0];
    }
}

// ---------------------------------------------------------------------------
// K3: bf16 MFMA coarse scoring + fused per-token top-8 over one N-half.
// Grid: (N_TOK/64)*2 blocks; block b: tokens (b>>1)*64, codes (b&1)*2048..+2048.
// 4 waves; wave w computes the 64x64 strip at cols nt*256 + w*64.
__global__ __launch_bounds__(256, 3) void coarse_kernel(
        const unsigned short* __restrict__ xb,
        const unsigned short* __restrict__ wb,
        float2* __restrict__ candp) {
    __shared__ __attribute__((aligned(16))) char smem[40960];
    unsigned short* sA = (unsigned short*)smem;            // [64][64] bf16, chunk-swizzled
    unsigned short* sB = (unsigned short*)(smem + 8192);   // [256][64] bf16, chunk-swizzled
    float* sS = (float*)smem;                              // 4 strips x [64][SPITCH] (reuse)
    float* mv = (float*)smem;                              // merge vals [64][32] (reuse)
    int*   mi = (int*)(smem + 8192);                       // merge idx  [64][32] (reuse)

    const int tid  = threadIdx.x;
    const int w    = tid >> 6;         // wave id 0..3
    const int l    = tid & 63;
    const int m0   = (blockIdx.x >> 1) * CBM;
    const int half = blockIdx.x & 1;
    const int n0   = half * NHALF;

    const int srow   = l >> 3;               // row within an 8-row staging group
    const int schunk = (l & 7) ^ srow;       // XOR-swizzled source 16B-chunk
    const int mrow   = l & 15;
    const int kq     = l >> 4;               // 0..3

    float bv[8]; int bi[8];
#pragma unroll
    for (int k = 0; k < 8; ++k) { bv[k] = -1e30f; bi[k] = k; }

    for (int nt = 0; nt < NT_STEPS; ++nt) {
        f32x4 acc[4][4];
#pragma unroll
        for (int i = 0; i < 4; ++i)
#pragma unroll
            for (int j = 0; j < 4; ++j) acc[i][j] = {0.0f, 0.0f, 0.0f, 0.0f};

        for (int kc = 0; kc < KC_STEPS; ++kc) {
            __syncthreads();   // prior LDS readers (frags / scan) done
            // stage A: wave w stages rows [w*16, w*16+16)
#pragma unroll
            for (int c = 0; c < 2; ++c) {
                int r0 = w * 16 + c * 8;
                const unsigned short* gp =
                    xb + (size_t)(m0 + r0 + srow) * DIM + kc * CBK + schunk * 8;
                __builtin_amdgcn_global_load_lds(
                    (const __attribute__((address_space(1))) void*)gp,
                    (__attribute__((address_space(3))) void*)(sA + r0 * 64), 16, 0, 0);
            }
            // stage B: wave w stages rows [w*64, w*64+64)
#pragma unroll
            for (int c = 0; c < 8; ++c) {
                int r0 = w * 64 + c * 8;
                const unsigned short* gp =
                    wb + (size_t)(n0 + nt * CBN + r0 + srow) * DIM + kc * CBK + schunk * 8;
                __builtin_amdgcn_global_load_lds(
                    (const __attribute__((address_space(1))) void*)gp,
                    (__attribute__((address_space(3))) void*)(sB + r0 * 64), 16, 0, 0);
            }
            __syncthreads();   // staged data visible

#pragma unroll
            for (int ks = 0; ks < 2; ++ks) {
                const int q = ks * 4 + kq;     // logical 16B k-chunk 0..7
                bf16x8 af[4], bfr[4];
#pragma unroll
                for (int i = 0; i < 4; ++i) {
                    int m = i * 16 + mrow;
                    af[i] = *(const bf16x8*)(sA + m * 64 + (q ^ (m & 7)) * 8);
                }
#pragma unroll
                for (int j = 0; j < 4; ++j) {
                    int n = w * 64 + j * 16 + mrow;
                    bfr[j] = *(const bf16x8*)(sB + n * 64 + (q ^ (n & 7)) * 8);
                }
#pragma unroll
                for (int i = 0; i < 4; ++i)
#pragma unroll
                    for (int j = 0; j < 4; ++j)
                        acc[i][j] = __builtin_amdgcn_mfma_f32_16x16x32_bf16(
                            af[i], bfr[j], acc[i][j], 0, 0, 0);
            }
        }

        // selection: 2 half-strip rounds (32 cols each)
#pragma unroll
        for (int h = 0; h < 2; ++h) {
            __syncthreads();   // frag reads (h=0) / previous scan (h=1) done
            float* strip = sS + w * (64 * SPITCH);
#pragma unroll
            for (int i = 0; i < 4; ++i)
#pragma unroll
                for (int jj = 0; jj < 2; ++jj) {
                    const int j = h * 2 + jj;
#pragma unroll
                    for (int r = 0; r < 4; ++r)
                        strip[(i * 16 + kq * 4 + r) * SPITCH + jj * 16 + mrow] = acc[i][j][r];
                }
            __syncthreads();
            // scan: thread (tok = tid&63, qq = tid>>6) scans strip qq's 32 cols
            int tok = tid & 63, qq = tid >> 6;
            const float4* sr = (const float4*)(sS + qq * (64 * SPITCH) + tok * SPITCH);
            int ib = n0 + nt * CBN + qq * 64 + h * 32;
#pragma unroll
            for (int c4 = 0; c4 < 8; ++c4) {
                float4 v = sr[c4];
                float m = fmaxf(fmaxf(v.x, v.y), fmaxf(v.z, v.w));
                if (m > bv[7]) {          // rare: divergent branch into insertion
                    top8_insert(v.x, ib + c4 * 4 + 0, bv, bi);
                    top8_insert(v.y, ib + c4 * 4 + 1, bv, bi);
                    top8_insert(v.z, ib + c4 * 4 + 2, bv, bi);
                    top8_insert(v.w, ib + c4 * 4 + 3, bv, bi);
                }
            }
        }
    }

    // merge the 4 col-quarter top-8 lists per token; emit (score, idx) pairs
    __syncthreads();
    {
        int tok = tid & 63, qq = tid >> 6;
#pragma unroll
        for (int k = 0; k < 8; ++k) {
            mv[tok * 32 + qq * 8 + k] = bv[k];
            mi[tok * 32 + qq * 8 + k] = bi[k];
        }
    }
    __syncthreads();
    if (tid < 64) {
        float fv[8]; int fi[8];
#pragma unroll
        for (int k = 0; k < 8; ++k) { fv[k] = -1e30f; fi[k] = k; }
        for (int t = 0; t < 32; ++t) top8_insert(mv[tid * 32 + t], mi[tid * 32 + t], fv, fi);
        float2* cp = candp + ((size_t)(m0 + tid) * 2 + half) * 8;
#pragma unroll
        for (int k = 0; k < 8; ++k) cp[k] = make_float2(fv[k], __int_as_float(fi[k]));
    }
}

// ---------------------------------------------------------------------------
// K3b: merge the two halves' top-8 lists -> final 8 candidate indices/token.
__global__ void merge_kernel(const float2* __restrict__ candp, int* __restrict__ cand8) {
    int tok = blockIdx.x * 256 + threadIdx.x;
    float bv[8]; int bi[8];
#pragma unroll
    for (int k = 0; k < 8; ++k) { bv[k] = -1e30f; bi[k] = k; }
    const float2* cp = candp + (size_t)tok * 16;
#pragma unroll
    for (int t = 0; t < 16; ++t) {
        float2 p = cp[t];
        top8_insert(p.x, __float_as_int(p.y), bv, bi);
    }
    int* o = cand8 + (size_t)tok * 8;
#pragma unroll
    for (int k = 0; k < 8; ++k) o[k] = bi[k];
}

// ---------------------------------------------------------------------------
// K4: f32-replicated dist over 8 candidates (np-exact), gather + MSE partial.
__global__ void refine_kernel(const float* __restrict__ x,
                              const float* __restrict__ embed,
                              const float* __restrict__ whf,
                              const float* __restrict__ t3_f,
                              const int* __restrict__ cand,
                              float* __restrict__ out,
                              double* __restrict__ partial) {
    __shared__ float part[4][32];
    __shared__ double wsum[4];
    const int wid  = threadIdx.x >> 6;
    const int lane = threadIdx.x & 63;
    const int tok  = blockIdx.x * 4 + wid;
    const float* f = x + (size_t)tok * DIM;

    if (lane < 32) {
        int base = (lane >> 3) * 128 + (lane & 7);
        float v = f[base];
        float r = __fmul_rn(v, v);
#pragma unroll
        for (int i = 1; i < 16; ++i) {
            float u = f[base + 8 * i];
            r = __fadd_rn(r, __fmul_rn(u, u));
        }
        part[wid][lane] = r;
    }
    __syncthreads();
    float t1 = pairwise_tree(part[wid]);

    float4 f0 = *(const float4*)(f + lane * 8);
    float4 f1 = *(const float4*)(f + lane * 8 + 4);

    float bd = 1e30f; int bc = 0x7fffffff;
    const int* cp = cand + (size_t)tok * 8;
#pragma unroll
    for (int k = 0; k < 8; ++k) {
        int c = cp[k];
        const float* wh = whf + (size_t)c * DIM + lane * 8;
        float4 w0 = *(const float4*)wh;
        float4 w1 = *(const float4*)(wh + 4);
        double s = (double)f0.x * w0.x + (double)f0.y * w0.y
                 + (double)f0.z * w0.z + (double)f0.w * w0.w
                 + (double)f1.x * w1.x + (double)f1.y * w1.y
                 + (double)f1.z * w1.z + (double)f1.w * w1.w;
#pragma unroll
        for (int off = 32; off > 0; off >>= 1) s += __shfl_xor(s, off);
        float mm = (float)s;
        float dist = __fadd_rn(__fsub_rn(t1, __fmul_rn(2.0f, mm)), t3_f[c]);
        if (dist < bd || (dist == bd && c < bc)) { bd = dist; bc = c; }
    }

    const float* eb = embed + (size_t)bc * DIM;
    double dsum = 0.0;
#pragma unroll
    for (int r = 0; r < DIM / 64; ++r) {
        int d = lane + 64 * r;
        float q = eb[d];
        out[(size_t)tok * DIM + d] = q;   // (quantize + quantize_1)*0.5 == quantize
        double dd = (double)q - (double)f[d];
        dsum += dd * dd;
    }
#pragma unroll
    for (int off = 32; off > 0; off >>= 1) dsum += __shfl_xor(dsum, off);
    if (lane == 0) wsum[wid] = dsum;
    __syncthreads();
    if (threadIdx.x == 0)
        partial[blockIdx.x] = wsum[0] + wsum[1] + wsum[2] + wsum[3];
}

// ---------------------------------------------------------------------------
__global__ void finalize_kernel(const double* __restrict__ partial,
                                float* __restrict__ out) {
    __shared__ double acc[4];
    int tid = threadIdx.x;
    double s = 0.0;
    for (int i = tid; i < N_TOK / 4; i += 256) s += partial[i];
#pragma unroll
    for (int off = 32; off > 0; off >>= 1) s += __shfl_xor(s, off);
    if ((tid & 63) == 0) acc[tid >> 6] = s;
    __syncthreads();
    if (tid == 0)
        out[(size_t)N_TOK * DIM] =
            (float)((acc[0] + acc[1] + acc[2] + acc[3]) * (1.0 / ((double)N_TOK * DIM)));
}

// ---------------------------------------------------------------------------
extern "C" void kernel_launch(void* const* d_in, const int* in_sizes, int n_in,
                              void* d_out, int out_size, void* d_ws, size_t ws_size,
                              hipStream_t stream) {
    const float* x     = (const float*)d_in[0];   // [32768, 512]
    const float* embed = (const float*)d_in[1];   // [4096, 512]
    float* out = (float*)d_out;                   // 16777216 + 1 floats

    char* wsb = (char*)d_ws;
    size_t off = 0;
    double* partial = (double*)(wsb + off); off += 65536;            // 8192 f64
    float*  n_f     = (float*) (wsb + off); off += 16384;
    float*  t3_f    = (float*) (wsb + off); off += 16384;
    float2* candp   = (float2*)(wsb + off); off += (size_t)N_TOK * 16 * 8;  // 4 MB
    int*    cand8   = (int*)   (wsb + off); off += (size_t)N_TOK * 8 * 4;   // 1 MB
    unsigned short* xb = (unsigned short*)(wsb + off); off += (size_t)N_TOK * DIM * 2;  // 32 MB
    unsigned short* wb = (unsigned short*)(wsb + off); off += (size_t)N_CODE * DIM * 2; // 4 MB
    float*  whf     = (float*) (wsb + off);                                  // 8 MB

    xcvt_kernel    <<<16384, 256, 0, stream>>>(x, xb);
    norms_kernel   <<<N_CODE, 64, 0, stream>>>(embed, n_f, t3_f);
    wcvt_kernel    <<<2048, 256, 0, stream>>>(embed, n_f, whf, wb);
    coarse_kernel  <<<(N_TOK / CBM) * 2, 256, 0, stream>>>(xb, wb, candp);
    merge_kernel   <<<N_TOK / 256, 256, 0, stream>>>(candp, cand8);
    refine_kernel  <<<N_TOK / 4, 256, 0, stream>>>(x, embed, whf, t3_f, cand8, out, partial);
    finalize_kernel<<<1, 256, 0, stream>>>(partial, out);
}